// Round 6
// baseline (66.689 us; speedup 1.0000x reference)
//
#include <hip/hip_runtime.h>
#include <math.h>

#define NCONCEPT 1024
#define TPB 256
#define UNROLL 4

typedef float fx4  __attribute__((ext_vector_type(4)));
// 4-byte-aligned float2: the (theta, omega) pair lives at byte offset 12e+4,
// which is dword- but not qword-aligned. gfx950 handles align-4 dwordx2.
typedef float fx2u __attribute__((ext_vector_type(2), aligned(4)));

// out[i] = 0.5 + 0.5 * ( cos(th2)*cos(th1) - sin(th2)*sin(th1)*cos(om1 + ph2) )
//        = 0.5 + 0.5 * ( A*c1 - s1*(Bc*co - Bs*so) )
// A = cos(th2), Bc = sin(th2)*cos(ph2), Bs = sin(th2)*sin(ph2);
// (th1, om1) = instance[i][1..2] (8 contiguous bytes); ph2/th2 = w[idx[i]][0/1].
// instance[i][0] and w[..][2] cancel out of <Z> exactly.
//
// Design (R6): consecutive lanes own consecutive elements; each lane loads its
// (theta, omega) pair with one dwordx2 -> a wave touches 6 lines / 512B payload
// per instruction (optimal given the dead phi column). idx/out are coalesced
// scalar dwords. No staging LDS, no loop barriers; LDS = 16 KB table only
// -> 8 blocks/CU (100% occupancy cap). Unroll x4 with loads batched for MLP.

__global__ __launch_bounds__(TPB) void vqc_kernel(
    const float* __restrict__ inst,   // [N,3] f32
    const int*   __restrict__ idx,    // [N]   i32
    const float* __restrict__ w,      // [NCONCEPT,3] f32
    float*       __restrict__ out,    // [N]   f32
    int n)
{
    __shared__ fx4 tab[NCONCEPT];     // (A, Bc, Bs, 0) — 16 KB

    for (int c = threadIdx.x; c < NCONCEPT; c += TPB) {
        float ph2 = w[c * 3 + 0];
        float th2 = w[c * 3 + 1];
        float sth2, cth2, sph2, cph2;
        __sincosf(th2, &sth2, &cth2);
        __sincosf(ph2, &sph2, &cph2);
        fx4 t; t.x = cth2; t.y = sth2 * cph2; t.z = sth2 * sph2; t.w = 0.0f;
        tab[c] = t;
    }
    __syncthreads();

    const int tid = blockIdx.x * TPB + threadIdx.x;
    const int T   = gridDim.x * TPB;

    int i = tid;
    for (; i + (UNROLL - 1) * T < n; i += UNROLL * T) {
        fx2u to_[UNROLL];
        int  id_[UNROLL];
        #pragma unroll
        for (int u = 0; u < UNROLL; ++u) {
            const int e = i + u * T;
            to_[u] = *(const fx2u*)(inst + (size_t)e * 3 + 1);
            id_[u] = idx[e];
        }
        #pragma unroll
        for (int u = 0; u < UNROLL; ++u) {
            const int e = i + u * T;
            fx4 t4 = tab[id_[u]];
            float s1, c1, so, co;
            __sincosf(to_[u].x, &s1, &c1);
            __sincosf(to_[u].y, &so, &co);
            float z = t4.x * c1 - s1 * (t4.y * co - t4.z * so);
            out[e] = fmaf(z, 0.5f, 0.5f);
        }
    }
    for (; i < n; i += T) {
        float th1 = inst[(size_t)i * 3 + 1];
        float om1 = inst[(size_t)i * 3 + 2];
        fx4 t4 = tab[idx[i]];
        float s1, c1, so, co;
        __sincosf(th1, &s1, &c1);
        __sincosf(om1, &so, &co);
        float z = t4.x * c1 - s1 * (t4.y * co - t4.z * so);
        out[i] = fmaf(z, 0.5f, 0.5f);
    }
}

extern "C" void kernel_launch(void* const* d_in, const int* in_sizes, int n_in,
                              void* d_out, int out_size, void* d_ws, size_t ws_size,
                              hipStream_t stream) {
    const float* inst = (const float*)d_in[0];   // [B,D,3] f32
    const int*   idx  = (const int*)d_in[1];     // [B,D]   i32
    const float* w    = (const float*)d_in[2];   // [NC,3]  f32
    float*       out  = (float*)d_out;           // [B,D]   f32

    const int n = in_sizes[1];                   // B*D elements
    // 16 KB LDS/block -> 8 blocks/CU (wave cap) -> 2048 resident blocks.
    vqc_kernel<<<2048, TPB, 0, stream>>>(inst, idx, w, out, n);
}

// Round 7
// 53.366 us; speedup vs baseline: 1.2497x; 1.2497x over previous
//
#include <hip/hip_runtime.h>
#include <math.h>

#define NCONCEPT 1024
#define TPB 256

typedef float fx4 __attribute__((ext_vector_type(4)));
typedef int   ix4 __attribute__((ext_vector_type(4)));

// out[i] = 0.5 + 0.5 * ( cos(th2)*cos(th1) - sin(th2)*sin(th1)*cos(om1 + ph2) )
// th1 = instance[i][1], om1 = instance[i][2]; ph2/th2 = w[idx[i]][0/1].
// instance[i][0] and w[..][2] cancel out of <Z> exactly.
//
// R7 = R1 (best so far, 64.5us) with ONE change: nontemporal stores for the
// write-once output stream, so it doesn't allocate in L2/L3 and evict the
// 268 MB input working set (which straddles the 256 MB Infinity Cache;
// rocprof showed L3 serving ~half the input reads). Loads stay cached --
// R3 measured nt-loads as a 1.7x regression.

__global__ __launch_bounds__(TPB) void vqc_kernel(
    const float* __restrict__ inst,   // [N,3] f32
    const int*   __restrict__ idx,    // [N]   i32
    const float* __restrict__ w,      // [NCONCEPT,3] f32
    float*       __restrict__ out,    // [N]   f32
    int n)
{
    __shared__ fx4 tab[NCONCEPT];     // (cos th2, sin th2, cos ph2, sin ph2)

    for (int c = threadIdx.x; c < NCONCEPT; c += TPB) {
        float ph2 = w[c * 3 + 0];
        float th2 = w[c * 3 + 1];
        float sth2, cth2, sph2, cph2;
        __sincosf(th2, &sth2, &cth2);
        __sincosf(ph2, &sph2, &cph2);
        fx4 t; t.x = cth2; t.y = sth2; t.z = cph2; t.w = sph2;
        tab[c] = t;
    }
    __syncthreads();

    const int tid    = blockIdx.x * TPB + threadIdx.x;
    const int stride = gridDim.x * TPB;
    const int nquads = n >> 2;

    const fx4* __restrict__ inst4 = (const fx4*)inst;
    const ix4* __restrict__ idx4  = (const ix4*)idx;
    fx4*       __restrict__ out4  = (fx4*)out;

    for (int q = tid; q < nquads; q += stride) {
        // 4 elements = 12 floats = 3x float4 (cached loads)
        fx4 a = inst4[q * 3 + 0];
        fx4 b = inst4[q * 3 + 1];
        fx4 c = inst4[q * 3 + 2];
        ix4 ix = idx4[q];

        float th[4] = { a.y, b.x, b.w, c.z };
        float om[4] = { a.z, b.y, c.x, c.w };
        int   id[4] = { ix.x, ix.y, ix.z, ix.w };

        float res[4];
        #pragma unroll
        for (int e = 0; e < 4; ++e) {
            fx4 t = tab[id[e]];          // cth2, sth2, cph2, sph2
            float s1, c1, so, co;
            __sincosf(th[e], &s1, &c1);
            __sincosf(om[e], &so, &co);
            float cop = co * t.z - so * t.w;          // cos(om1 + ph2)
            float z   = t.x * c1 - t.y * s1 * cop;
            res[e] = fmaf(z, 0.5f, 0.5f);
        }
        fx4 r; r.x = res[0]; r.y = res[1]; r.z = res[2]; r.w = res[3];
        __builtin_nontemporal_store(r, &out4[q]);   // write-once: don't pollute L2/L3
    }

    // scalar tail (n not divisible by 4) — no-op for this problem size
    for (int i = (nquads << 2) + tid; i < n; i += stride) {
        float th1 = inst[i * 3 + 1];
        float om1 = inst[i * 3 + 2];
        fx4 t = tab[idx[i]];
        float s1, c1, so, co;
        __sincosf(th1, &s1, &c1);
        __sincosf(om1, &so, &co);
        float cop = co * t.z - so * t.w;
        float z   = t.x * c1 - t.y * s1 * cop;
        out[i] = fmaf(z, 0.5f, 0.5f);
    }
}

extern "C" void kernel_launch(void* const* d_in, const int* in_sizes, int n_in,
                              void* d_out, int out_size, void* d_ws, size_t ws_size,
                              hipStream_t stream) {
    const float* inst = (const float*)d_in[0];   // [B,D,3] f32
    const int*   idx  = (const int*)d_in[1];     // [B,D]   i32
    const float* w    = (const float*)d_in[2];   // [NC,3]  f32
    float*       out  = (float*)d_out;           // [B,D]   f32

    const int n = in_sizes[1];                   // B*D elements
    vqc_kernel<<<2048, TPB, 0, stream>>>(inst, idx, w, out, n);
}